// Round 6
// baseline (348.362 us; speedup 1.0000x reference)
//
#include <hip/hip_runtime.h>
#include <hip/hip_bf16.h>

#define BB   32768
#define LL   1024
#define FEA  1028
#define MEM  50
#define DATE 32

typedef float  f32x4  __attribute__((ext_vector_type(4)));
typedef __bf16 bf16x8 __attribute__((ext_vector_type(8)));

__device__ __forceinline__ float wave_max(float v) {
    #pragma unroll
    for (int off = 32; off; off >>= 1) v = fmaxf(v, __shfl_xor(v, off));
    return v;
}
__device__ __forceinline__ float wave_sum(float v) {
    #pragma unroll
    for (int off = 32; off; off >>= 1) v += __shfl_xor(v, off);
    return v;
}
// tanh via __expf: exact at both saturations, ~1e-6 abs error in between.
__device__ __forceinline__ float fast_tanh(float v) {
    float e = __expf(2.f * v);
    return 1.f - 2.f / (e + 1.f);
}

// wc[n*64+k] = sum_j convt_w[j] * mem_W[k][n+4-j], zero-padded k in [50,64)
__global__ __launch_bounds__(256) void prep_wc(
        const float* __restrict__ convt_w,
        const float* __restrict__ mem_W,
        __bf16* __restrict__ wc) {
    int idx = blockIdx.x * 256 + threadIdx.x;   // 65536
    int n = idx >> 6, k = idx & 63;
    float acc = 0.f;
    if (k < MEM) {
        #pragma unroll
        for (int j = 0; j < 5; ++j)
            acc += convt_w[j] * mem_W[k * FEA + n + 4 - j];
    }
    wc[n * 64 + k] = (__bf16)acc;
}

// ---------------- K1 (DIAGNOSTIC x2): pure x-GEMV -> w/b -------------------
// grid 4096: blocks [0,2048) = pass 1, [2048,4096) = pass 2 (identical rows,
// identical values, idempotent rewrite). Doubles the dispatch time so this
// kernel rises above the 80us harness fills into rocprof's top-5 with its own
// counters. Body is the round-3 (verified) GEMV, 16 rows/block, 4 rows/wave.
__global__ __launch_bounds__(256) void wb_gemv(
        const float* __restrict__ x,
        const float* __restrict__ fcw_w, const float* __restrict__ fcw_b,
        const float* __restrict__ fcb_w, const float* __restrict__ fcb_b,
        float* __restrict__ out) {
    const int lane = threadIdx.x & 63;
    const int wid  = threadIdx.x >> 6;
    const int b0   = (blockIdx.x & 2047) * 16;

    f32x4 wv[4], bv[4];
    #pragma unroll
    for (int c = 0; c < 4; ++c) {
        wv[c] = *(const f32x4*)(fcw_w + c * 256 + lane * 4);
        bv[c] = *(const f32x4*)(fcb_w + c * 256 + lane * 4);
    }
    f32x4 xv[4][4];
    #pragma unroll
    for (int rr = 0; rr < 4; ++rr)
        #pragma unroll
        for (int c = 0; c < 4; ++c)
            xv[rr][c] = *(const f32x4*)(x + (size_t)(b0 + wid * 4 + rr) * LL
                                          + c * 256 + lane * 4);
    float fwb = fcw_b[0], fbb = fcb_b[0];
    #pragma unroll
    for (int rr = 0; rr < 4; ++rr) {
        int r = wid * 4 + rr;
        float aw = 0.f, ab = 0.f;
        #pragma unroll
        for (int c = 0; c < 4; ++c)
            #pragma unroll
            for (int j = 0; j < 4; ++j) {
                aw += xv[rr][c][j] * wv[c][j];
                ab += xv[rr][c][j] * bv[c][j];
            }
        #pragma unroll
        for (int off = 1; off <= 32; off <<= 1) {
            aw += __shfl_xor(aw, off);
            ab += __shfl_xor(ab, off);
        }
        if (lane == 0) {
            out[(size_t)BB * LL + (b0 + r)]      = fast_tanh(aw + fwb) * 0.5f + 1.0f;
            out[(size_t)BB * LL + BB + (b0 + r)] = fast_tanh(ab + fbb) * 0.5f;
        }
    }
}

// ---------------- K2 (DIAGNOSTIC x2): att + MFMA + store engine ------------
// grid 4096, same two-pass duplication as K1. Body = round-3 verified kernel.
__global__ __launch_bounds__(256) void memconv_main(
        const float* __restrict__ dv,
        const float* __restrict__ dW,
        const __bf16* __restrict__ wc,
        float* __restrict__ out) {
    __shared__ __bf16 att_s[16 * 72];          // [row][k], 144B stride
    __shared__ float  w_s[16], b_s[16];
    __shared__ float  stage[4][16 * 72];       // per-wave D staging

    const int lane = threadIdx.x & 63;
    const int wid  = threadIdx.x >> 6;
    const int cg   = lane & 15;
    const int kg   = lane >> 4;
    const int b0   = (blockIdx.x & 2047) * 16;

    // w/b readback for this block's 16 rows (written by wb_gemv)
    if (threadIdx.x < 16) {
        w_s[threadIdx.x] = out[(size_t)BB * LL + b0 + threadIdx.x];
        b_s[threadIdx.x] = out[(size_t)BB * LL + BB + b0 + threadIdx.x];
    }

    // ---- Phase 0: att for rows wid*4 .. wid*4+3 ----
    {
        int m = lane < MEM ? lane : MEM - 1;
        float dwv[DATE];
        const f32x4* dwp = (const f32x4*)(dW + m * DATE);
        #pragma unroll
        for (int c = 0; c < 8; ++c) {
            f32x4 v = dwp[c];
            #pragma unroll
            for (int j = 0; j < 4; ++j) dwv[c * 4 + j] = v[j];
        }
        #pragma unroll
        for (int rr = 0; rr < 4; ++rr) {
            int r = wid * 4 + rr;
            const f32x4* dvp = (const f32x4*)(dv + (size_t)(b0 + r) * DATE);
            float sc = 0.f;
            #pragma unroll
            for (int c = 0; c < 8; ++c) {
                f32x4 v = dvp[c];
                #pragma unroll
                for (int j = 0; j < 4; ++j) sc += v[j] * dwv[c * 4 + j];
            }
            float scm = (lane < MEM) ? sc : -1e30f;
            float mx  = wave_max(scm);
            float e   = (lane < MEM) ? __expf(sc - mx) : 0.f;
            float s   = wave_sum(e);
            float p   = e / s;
            float d   = p - 0.0025f;
            float p2  = (d > 0.f) ? p * d / (d + 1e-12f) : 0.f;
            float s2  = wave_sum(p2) + 1e-12f;
            float att = p2 / s2;
            att_s[r * 72 + lane] = (lane < MEM) ? (__bf16)att : (__bf16)0.f;
        }
    }
    __syncthreads();

    // ---- Phase B: transposed-operand MFMA + LDS-staged contiguous stores ----
    {
        bf16x8 bfr0 = *(const bf16x8*)(att_s + cg * 72 + kg * 8);
        bf16x8 bfr1 = *(const bf16x8*)(att_s + cg * 72 + 32 + kg * 8);
        float* st = stage[wid];
        const int n0 = wid * 256;
        #pragma unroll
        for (int R = 0; R < 4; ++R) {
            #pragma unroll
            for (int t = 0; t < 4; ++t) {
                int n = n0 + (R * 4 + t) * 16 + cg;
                bf16x8 a0 = *(const bf16x8*)(wc + n * 64 + kg * 8);
                bf16x8 a1 = *(const bf16x8*)(wc + n * 64 + 32 + kg * 8);
                f32x4 acc = {0.f, 0.f, 0.f, 0.f};
                acc = __builtin_amdgcn_mfma_f32_16x16x32_bf16(a0, bfr0, acc, 0, 0, 0);
                acc = __builtin_amdgcn_mfma_f32_16x16x32_bf16(a1, bfr1, acc, 0, 0, 0);
                *(f32x4*)(st + cg * 72 + t * 16 + kg * 4) = acc;
            }
            #pragma unroll
            for (int j = 0; j < 4; ++j) {
                int row = j * 4 + (lane >> 4);
                int nl  = (lane & 15) * 4;
                f32x4 v = *(const f32x4*)(st + row * 72 + nl);
                float w = w_s[row], bi = b_s[row];
                f32x4 o;
                #pragma unroll
                for (int k = 0; k < 4; ++k) o[k] = v[k] * w + bi;
                *(f32x4*)(out + (size_t)(b0 + row) * LL + n0 + R * 64 + nl) = o;
            }
        }
    }
}

extern "C" void kernel_launch(void* const* d_in, const int* in_sizes, int n_in,
                              void* d_out, int out_size, void* d_ws, size_t ws_size,
                              hipStream_t stream) {
    const float* x     = (const float*)d_in[0];
    const float* dv    = (const float*)d_in[1];
    // d_in[2] = conv_w: DEAD CODE in the reference (st is overwritten by st_mem)
    const float* convt = (const float*)d_in[3];
    const float* memW  = (const float*)d_in[4];
    const float* dateW = (const float*)d_in[5];
    const float* fcww  = (const float*)d_in[6];
    const float* fcwb  = (const float*)d_in[7];
    const float* fcbw  = (const float*)d_in[8];
    const float* fcbb  = (const float*)d_in[9];
    float* out = (float*)d_out;
    __bf16* wc = (__bf16*)d_ws;   // 64K bf16 = 128 KB

    prep_wc     <<<256,  256, 0, stream>>>(convt, memW, wc);
    wb_gemv     <<<4096, 256, 0, stream>>>(x, fcww, fcwb, fcbw, fcbb, out);
    memconv_main<<<4096, 256, 0, stream>>>(dv, dateW, wc, out);
}

// Round 7
// 294.994 us; speedup vs baseline: 1.1809x; 1.1809x over previous
//
#include <hip/hip_runtime.h>
#include <hip/hip_bf16.h>

#define BB   32768
#define LL   1024
#define FEA  1028
#define MEM  50
#define DATE 32

typedef float  f32x4  __attribute__((ext_vector_type(4)));
typedef __bf16 bf16x8 __attribute__((ext_vector_type(8)));

__device__ __forceinline__ float wave_max(float v) {
    #pragma unroll
    for (int off = 32; off; off >>= 1) v = fmaxf(v, __shfl_xor(v, off));
    return v;
}
__device__ __forceinline__ float wave_sum(float v) {
    #pragma unroll
    for (int off = 32; off; off >>= 1) v += __shfl_xor(v, off);
    return v;
}
// tanh via __expf: exact at both saturations, ~1e-6 abs error in between.
__device__ __forceinline__ float fast_tanh(float v) {
    float e = __expf(2.f * v);
    return 1.f - 2.f / (e + 1.f);
}

// ---------------- K1: all reads + small products ---------------------------
// blocks [0, 2048):    wb GEMV over x (16 rows/block) -> out tail  [read stream]
// blocks [2048, 4096): att softmax (16 rows/block) -> att_g bf16[32768][64]
// blocks [4096, 4352): wc[n*64+k] = sum_j convt_w[j]*mem_W[k][n+4-j]
__global__ __launch_bounds__(256) void prep_and_wb(
        const float* __restrict__ convt_w,
        const float* __restrict__ mem_W,
        const float* __restrict__ x,
        const float* __restrict__ fcw_w, const float* __restrict__ fcw_b,
        const float* __restrict__ fcb_w, const float* __restrict__ fcb_b,
        const float* __restrict__ dv,
        const float* __restrict__ dW,
        __bf16* __restrict__ wc,
        __bf16* __restrict__ att_g,
        float* __restrict__ out) {
    const int lane = threadIdx.x & 63;
    const int wid  = threadIdx.x >> 6;

    if (blockIdx.x >= 4096) {              // ---- wc prep ----
        int idx = (blockIdx.x - 4096) * 256 + threadIdx.x;   // 65536
        int n = idx >> 6, k = idx & 63;
        float acc = 0.f;
        if (k < MEM) {
            #pragma unroll
            for (int j = 0; j < 5; ++j)
                acc += convt_w[j] * mem_W[k * FEA + n + 4 - j];
        }
        wc[n * 64 + k] = (__bf16)acc;
        return;
    }

    if (blockIdx.x >= 2048) {              // ---- att softmax ----
        const int b0 = (blockIdx.x - 2048) * 16;
        int m = lane < MEM ? lane : MEM - 1;
        float dwv[DATE];
        const f32x4* dwp = (const f32x4*)(dW + m * DATE);
        #pragma unroll
        for (int c = 0; c < 8; ++c) {
            f32x4 v = dwp[c];
            #pragma unroll
            for (int j = 0; j < 4; ++j) dwv[c * 4 + j] = v[j];
        }
        #pragma unroll
        for (int rr = 0; rr < 4; ++rr) {
            int r = b0 + wid * 4 + rr;
            const f32x4* dvp = (const f32x4*)(dv + (size_t)r * DATE);
            float sc = 0.f;
            #pragma unroll
            for (int c = 0; c < 8; ++c) {
                f32x4 v = dvp[c];
                #pragma unroll
                for (int j = 0; j < 4; ++j) sc += v[j] * dwv[c * 4 + j];
            }
            float scm = (lane < MEM) ? sc : -1e30f;
            float mx  = wave_max(scm);
            float e   = (lane < MEM) ? __expf(sc - mx) : 0.f;
            float s   = wave_sum(e);
            float p   = e / s;
            float d   = p - 0.0025f;
            float p2  = (d > 0.f) ? p * d / (d + 1e-12f) : 0.f;
            float s2  = wave_sum(p2) + 1e-12f;
            float att = p2 / s2;
            att_g[(size_t)r * 64 + lane] = (lane < MEM) ? (__bf16)att : (__bf16)0.f;
        }
        return;
    }

    // ---- wb GEMV: 16 rows/block, 4 rows/wave, full-row contiguous loads ----
    const int b0 = blockIdx.x * 16;
    f32x4 wv[4], bv[4];
    #pragma unroll
    for (int c = 0; c < 4; ++c) {
        wv[c] = *(const f32x4*)(fcw_w + c * 256 + lane * 4);
        bv[c] = *(const f32x4*)(fcb_w + c * 256 + lane * 4);
    }
    f32x4 xv[4][4];
    #pragma unroll
    for (int rr = 0; rr < 4; ++rr)
        #pragma unroll
        for (int c = 0; c < 4; ++c)
            xv[rr][c] = *(const f32x4*)(x + (size_t)(b0 + wid * 4 + rr) * LL
                                          + c * 256 + lane * 4);
    float fwb = fcw_b[0], fbb = fcb_b[0];
    #pragma unroll
    for (int rr = 0; rr < 4; ++rr) {
        int r = wid * 4 + rr;
        float aw = 0.f, ab = 0.f;
        #pragma unroll
        for (int c = 0; c < 4; ++c)
            #pragma unroll
            for (int j = 0; j < 4; ++j) {
                aw += xv[rr][c][j] * wv[c][j];
                ab += xv[rr][c][j] * bv[c][j];
            }
        #pragma unroll
        for (int off = 1; off <= 32; off <<= 1) {
            aw += __shfl_xor(aw, off);
            ab += __shfl_xor(ab, off);
        }
        if (lane == 0) {
            out[(size_t)BB * LL + (b0 + r)]      = fast_tanh(aw + fwb) * 0.5f + 1.0f;
            out[(size_t)BB * LL + BB + (b0 + r)] = fast_tanh(ab + fbb) * 0.5f;
        }
    }
}

// ---------------- K2: register-burst store engine --------------------------
// No LDS, no barrier, no shfl. Each wave owns 16 batches x 256 n:
//   block b -> batches b*16..b*16+15; wave wid -> n in [wid*256, wid*256+256).
// MFMA acc layout: lane (cg,kg) holds D[batch=b0+cg][n = n0+t*16+kg*4+{0..3}]
// -> per store instruction 16 batches x 64B contiguous chunks (same 64B-granule
// count as the old LDS-staged 256B segments; FETCH=5MB in r6 proved no RMW).
// Compute ALL 16 tiles into regs -> scale by w/b -> sched_barrier ->
// 16 back-to-back 1KB stores: store queue stays full (fill-kernel regime).
__global__ __launch_bounds__(256, 4) void memconv_store(
        const __bf16* __restrict__ wc,
        const __bf16* __restrict__ att_g,
        const float* __restrict__ wb,      // = out + BB*LL (w at 0, b at +BB)
        float* __restrict__ out) {
    const int lane = threadIdx.x & 63;
    const int wid  = threadIdx.x >> 6;
    const int cg   = lane & 15;
    const int kg   = lane >> 4;
    const int b0   = blockIdx.x * 16;
    const int n0   = wid * 256;

    // B fragments: att rows b0..b0+15 (bf16, stride 64, zero-padded k>=50)
    bf16x8 bfr0 = *(const bf16x8*)(att_g + (size_t)(b0 + cg) * 64 + kg * 8);
    bf16x8 bfr1 = *(const bf16x8*)(att_g + (size_t)(b0 + cg) * 64 + 32 + kg * 8);
    // per-lane batch is cg -> w/b load directly, no shfl
    float w  = wb[b0 + cg];
    float bi = wb[BB + b0 + cg];

    f32x4 acc[16];
    #pragma unroll
    for (int t = 0; t < 16; ++t) {
        int n = n0 + t * 16 + cg;
        bf16x8 a0 = *(const bf16x8*)(wc + n * 64 + kg * 8);
        bf16x8 a1 = *(const bf16x8*)(wc + n * 64 + 32 + kg * 8);
        f32x4 z = {0.f, 0.f, 0.f, 0.f};
        z      = __builtin_amdgcn_mfma_f32_16x16x32_bf16(a0, bfr0, z, 0, 0, 0);
        acc[t] = __builtin_amdgcn_mfma_f32_16x16x32_bf16(a1, bfr1, z, 0, 0, 0);
    }
    #pragma unroll
    for (int t = 0; t < 16; ++t) {
        #pragma unroll
        for (int k = 0; k < 4; ++k) acc[t][k] = acc[t][k] * w + bi;
    }
    __builtin_amdgcn_sched_barrier(0);   // pin the store burst after all compute
    float* dst = out + (size_t)(b0 + cg) * LL + n0 + kg * 4;
    #pragma unroll
    for (int t = 0; t < 16; ++t)
        *(f32x4*)(dst + t * 16) = acc[t];
}

extern "C" void kernel_launch(void* const* d_in, const int* in_sizes, int n_in,
                              void* d_out, int out_size, void* d_ws, size_t ws_size,
                              hipStream_t stream) {
    const float* x     = (const float*)d_in[0];
    const float* dv    = (const float*)d_in[1];
    // d_in[2] = conv_w: DEAD CODE in the reference (st is overwritten by st_mem)
    const float* convt = (const float*)d_in[3];
    const float* memW  = (const float*)d_in[4];
    const float* dateW = (const float*)d_in[5];
    const float* fcww  = (const float*)d_in[6];
    const float* fcwb  = (const float*)d_in[7];
    const float* fcbw  = (const float*)d_in[8];
    const float* fcbb  = (const float*)d_in[9];
    float* out = (float*)d_out;
    __bf16* wc    = (__bf16*)d_ws;            // 65536 bf16 = 128 KB
    __bf16* att_g = (__bf16*)d_ws + 65536;    // 32768*64 bf16 = 4 MB

    prep_and_wb  <<<4352, 256, 0, stream>>>(convt, memW, x, fcww, fcwb, fcbw, fcbb,
                                            dv, dateW, wc, att_g, out);
    memconv_store<<<BB / 16, 256, 0, stream>>>(wc, att_g, out + (size_t)BB * LL, out);
}

// Round 8
// 290.305 us; speedup vs baseline: 1.2000x; 1.0162x over previous
//
#include <hip/hip_runtime.h>
#include <hip/hip_bf16.h>

#define BB   32768
#define LL   1024
#define FEA  1028
#define MEM  50
#define DATE 32

typedef float  f32x4  __attribute__((ext_vector_type(4)));
typedef __bf16 bf16x8 __attribute__((ext_vector_type(8)));

// tanh via __expf: exact at both saturations, ~1e-6 abs error in between.
__device__ __forceinline__ float fast_tanh(float v) {
    float e = __expf(2.f * v);
    return 1.f - 2.f / (e + 1.f);
}

// wc[n*64+k] = sum_j convt_w[j] * mem_W[k][n+4-j], zero-padded k in [50,64)
__global__ __launch_bounds__(256) void prep_wc(
        const float* __restrict__ convt_w,
        const float* __restrict__ mem_W,
        __bf16* __restrict__ wc) {
    int idx = blockIdx.x * 256 + threadIdx.x;   // 65536
    int n = idx >> 6, k = idx & 63;
    float acc = 0.f;
    if (k < MEM) {
        #pragma unroll
        for (int j = 0; j < 5; ++j)
            acc += convt_w[j] * mem_W[k * FEA + n + 4 - j];
    }
    wc[n * 64 + k] = (__bf16)acc;
}

// Fused kernel, round-8: FULL-ROW LINEAR STORES.
// Phase B stages the entire 16x1024 f32 output tile in LDS (66KB), then each
// wave flushes 4 COMPLETE rows as pure linear streams (1KB lane-contiguous per
// inst, sequential insts, wave writes contiguous 16KB, block contiguous 64KB)
// -- the exact address pattern of the 6.7 TB/s harness fill kernel.
// Everything before Phase B is the verified round-5 body.
__global__ __launch_bounds__(256) void memconv_fused3(
        const float* __restrict__ x,
        const float* __restrict__ dv,
        const float* __restrict__ dW,
        const float* __restrict__ fcw_w, const float* __restrict__ fcw_b,
        const float* __restrict__ fcb_w, const float* __restrict__ fcb_b,
        const __bf16* __restrict__ wc,
        float* __restrict__ out) {
    __shared__ __bf16 att_s[16 * 72];          // [row][k], 144B stride
    __shared__ float  w_s[16], b_s[16];
    __shared__ float  stage[16][1028];         // full 16-row f32 tile, +4 pad

    const int lane = threadIdx.x & 63;
    const int wid  = threadIdx.x >> 6;
    const int cg   = lane & 15;
    const int kg   = lane >> 4;
    const int b0   = blockIdx.x * 16;

    // ---- issue long-latency loads early: fc rows + first 2 x rows ----
    f32x4 wv[4], bv[4];
    #pragma unroll
    for (int c = 0; c < 4; ++c) {
        wv[c] = *(const f32x4*)(fcw_w + c * 256 + lane * 4);
        bv[c] = *(const f32x4*)(fcb_w + c * 256 + lane * 4);
    }
    f32x4 xv0[2][4];
    #pragma unroll
    for (int rr = 0; rr < 2; ++rr)
        #pragma unroll
        for (int c = 0; c < 4; ++c)
            xv0[rr][c] = *(const f32x4*)(x + (size_t)(b0 + wid * 4 + rr) * LL
                                           + c * 256 + lane * 4);

    // ---- att for rows wid*4..+3, overlapped with x loads ----
    {
        int m = lane < MEM ? lane : MEM - 1;
        float dwv[DATE];
        const f32x4* dwp = (const f32x4*)(dW + m * DATE);
        #pragma unroll
        for (int c = 0; c < 8; ++c) {
            f32x4 v = dwp[c];
            #pragma unroll
            for (int j = 0; j < 4; ++j) dwv[c * 4 + j] = v[j];
        }
        float e[4];
        #pragma unroll
        for (int rr = 0; rr < 4; ++rr) {
            const f32x4* dvp = (const f32x4*)(dv + (size_t)(b0 + wid * 4 + rr) * DATE);
            float sc = 0.f;
            #pragma unroll
            for (int c = 0; c < 8; ++c) {
                f32x4 v = dvp[c];
                #pragma unroll
                for (int j = 0; j < 4; ++j) sc += v[j] * dwv[c * 4 + j];
            }
            e[rr] = (lane < MEM) ? __expf(sc) : 0.f;   // no max-subtract
        }
        float s[4] = {e[0], e[1], e[2], e[3]};
        #pragma unroll
        for (int off = 32; off; off >>= 1) {
            #pragma unroll
            for (int rr = 0; rr < 4; ++rr) s[rr] += __shfl_xor(s[rr], off);
        }
        float p2[4];
        #pragma unroll
        for (int rr = 0; rr < 4; ++rr) {
            float p = e[rr] / s[rr];
            float d = p - 0.0025f;
            p2[rr]  = (d > 0.f) ? p * d / (d + 1e-12f) : 0.f;
        }
        float s2[4] = {p2[0], p2[1], p2[2], p2[3]};
        #pragma unroll
        for (int off = 32; off; off >>= 1) {
            #pragma unroll
            for (int rr = 0; rr < 4; ++rr) s2[rr] += __shfl_xor(s2[rr], off);
        }
        #pragma unroll
        for (int rr = 0; rr < 4; ++rr) {
            float att = p2[rr] / (s2[rr] + 1e-12f);
            att_s[(wid * 4 + rr) * 72 + lane] = (lane < MEM) ? (__bf16)att : (__bf16)0.f;
        }
    }

    // ---- second half of x rows ----
    f32x4 xv1[2][4];
    #pragma unroll
    for (int rr = 0; rr < 2; ++rr)
        #pragma unroll
        for (int c = 0; c < 4; ++c)
            xv1[rr][c] = *(const f32x4*)(x + (size_t)(b0 + wid * 4 + 2 + rr) * LL
                                           + c * 256 + lane * 4);

    // ---- GEMV for w/b: interleaved butterfly chains, fast tanh ----
    {
        float aw[4], ab[4];
        #pragma unroll
        for (int rr = 0; rr < 2; ++rr) {
            float sa = 0.f, sb = 0.f;
            #pragma unroll
            for (int c = 0; c < 4; ++c)
                #pragma unroll
                for (int j = 0; j < 4; ++j) {
                    sa += xv0[rr][c][j] * wv[c][j];
                    sb += xv0[rr][c][j] * bv[c][j];
                }
            aw[rr] = sa; ab[rr] = sb;
        }
        #pragma unroll
        for (int rr = 0; rr < 2; ++rr) {
            float sa = 0.f, sb = 0.f;
            #pragma unroll
            for (int c = 0; c < 4; ++c)
                #pragma unroll
                for (int j = 0; j < 4; ++j) {
                    sa += xv1[rr][c][j] * wv[c][j];
                    sb += xv1[rr][c][j] * bv[c][j];
                }
            aw[2 + rr] = sa; ab[2 + rr] = sb;
        }
        #pragma unroll
        for (int off = 1; off <= 32; off <<= 1) {
            #pragma unroll
            for (int rr = 0; rr < 4; ++rr) {
                aw[rr] += __shfl_xor(aw[rr], off);
                ab[rr] += __shfl_xor(ab[rr], off);
            }
        }
        if (lane == 0) {
            float fwb = fcw_b[0], fbb = fcb_b[0];
            #pragma unroll
            for (int rr = 0; rr < 4; ++rr) {
                int r = wid * 4 + rr;
                float w  = fast_tanh(aw[rr] + fwb) * 0.5f + 1.0f;
                float bi = fast_tanh(ab[rr] + fbb) * 0.5f;
                w_s[r] = w; b_s[r] = bi;
                out[(size_t)BB * LL + (b0 + r)]      = w;
                out[(size_t)BB * LL + BB + (b0 + r)] = bi;
            }
        }
    }
    __syncthreads();

    // ---- Phase B1: MFMA, stage FULL tile into LDS ----
    // A = wc (m = n-dim), B = att (col = batch). Lane (cg,kg), reg j holds
    // D[n = n0 + t*16 + kg*4 + j][batch = b0 + cg]. Wave wid owns cols
    // [wid*256, wid*256+256) for ALL 16 batches.
    {
        bf16x8 bfr0 = *(const bf16x8*)(att_s + cg * 72 + kg * 8);
        bf16x8 bfr1 = *(const bf16x8*)(att_s + cg * 72 + 32 + kg * 8);
        const int n0 = wid * 256;
        #pragma unroll
        for (int R = 0; R < 4; ++R) {
            #pragma unroll
            for (int t = 0; t < 4; ++t) {
                int n = n0 + R * 64 + t * 16 + cg;
                bf16x8 a0 = *(const bf16x8*)(wc + n * 64 + kg * 8);
                bf16x8 a1 = *(const bf16x8*)(wc + n * 64 + 32 + kg * 8);
                f32x4 acc = {0.f, 0.f, 0.f, 0.f};
                acc = __builtin_amdgcn_mfma_f32_16x16x32_bf16(a0, bfr0, acc, 0, 0, 0);
                acc = __builtin_amdgcn_mfma_f32_16x16x32_bf16(a1, bfr1, acc, 0, 0, 0);
                *(f32x4*)(&stage[cg][n0 + R * 64 + t * 16 + kg * 4]) = acc;
            }
        }
    }
    __syncthreads();

    // ---- Phase B2: linear flush. Wave wid owns COMPLETE rows wid*4..+3. ----
    // Each inst: 64 lanes x 16B = 1KB fully contiguous; 4 insts walk one 4KB
    // row; the wave's 4 rows are consecutive -> contiguous 16KB per wave.
    {
        #pragma unroll
        for (int rr = 0; rr < 4; ++rr) {
            int row = wid * 4 + rr;
            float w = w_s[row], bi = b_s[row];
            float* dst = out + (size_t)(b0 + row) * LL;
            #pragma unroll
            for (int q = 0; q < 4; ++q) {
                f32x4 v = *(const f32x4*)(&stage[row][q * 256 + lane * 4]);
                f32x4 o;
                #pragma unroll
                for (int k = 0; k < 4; ++k) o[k] = v[k] * w + bi;
                *(f32x4*)(dst + q * 256 + lane * 4) = o;
            }
        }
    }
}

extern "C" void kernel_launch(void* const* d_in, const int* in_sizes, int n_in,
                              void* d_out, int out_size, void* d_ws, size_t ws_size,
                              hipStream_t stream) {
    const float* x     = (const float*)d_in[0];
    const float* dv    = (const float*)d_in[1];
    // d_in[2] = conv_w: DEAD CODE in the reference (st is overwritten by st_mem)
    const float* convt = (const float*)d_in[3];
    const float* memW  = (const float*)d_in[4];
    const float* dateW = (const float*)d_in[5];
    const float* fcww  = (const float*)d_in[6];
    const float* fcwb  = (const float*)d_in[7];
    const float* fcbw  = (const float*)d_in[8];
    const float* fcbb  = (const float*)d_in[9];
    float* out = (float*)d_out;
    __bf16* wc = (__bf16*)d_ws;   // 64K bf16 = 128 KB

    prep_wc       <<<256,     256, 0, stream>>>(convt, memW, wc);
    memconv_fused3<<<BB / 16, 256, 0, stream>>>(x, dv, dateW, fcww, fcwb, fcbw, fcbb, wc, out);
}

// Round 9
// 287.519 us; speedup vs baseline: 1.2116x; 1.0097x over previous
//
#include <hip/hip_runtime.h>
#include <hip/hip_bf16.h>

#define BB   32768
#define LL   1024
#define FEA  1028
#define MEM  50
#define DATE 32

typedef float  f32x4  __attribute__((ext_vector_type(4)));
typedef __bf16 bf16x8 __attribute__((ext_vector_type(8)));

__device__ __forceinline__ float wave_max(float v) {
    #pragma unroll
    for (int off = 32; off; off >>= 1) v = fmaxf(v, __shfl_xor(v, off));
    return v;
}
__device__ __forceinline__ float wave_sum(float v) {
    #pragma unroll
    for (int off = 32; off; off >>= 1) v += __shfl_xor(v, off);
    return v;
}
// tanh via __expf: exact at both saturations, ~1e-6 abs error in between.
__device__ __forceinline__ float fast_tanh(float v) {
    float e = __expf(2.f * v);
    return 1.f - 2.f / (e + 1.f);
}

// ---------------- K1: all reads + small products ---------------------------
// blocks [0, 2048):    wb GEMV over x (16 rows/block) -> out tail  [read stream]
// blocks [2048, 4096): att softmax (16 rows/block) -> att_g bf16[32768][64]
// blocks [4096, 4352): wc[n*64+k] = sum_j convt_w[j]*mem_W[k][n+4-j]
__global__ __launch_bounds__(256) void prep_and_wb(
        const float* __restrict__ convt_w,
        const float* __restrict__ mem_W,
        const float* __restrict__ x,
        const float* __restrict__ fcw_w, const float* __restrict__ fcw_b,
        const float* __restrict__ fcb_w, const float* __restrict__ fcb_b,
        const float* __restrict__ dv,
        const float* __restrict__ dW,
        __bf16* __restrict__ wc,
        __bf16* __restrict__ att_g,
        float* __restrict__ out) {
    const int lane = threadIdx.x & 63;
    const int wid  = threadIdx.x >> 6;

    if (blockIdx.x >= 4096) {              // ---- wc prep ----
        int idx = (blockIdx.x - 4096) * 256 + threadIdx.x;   // 65536
        int n = idx >> 6, k = idx & 63;
        float acc = 0.f;
        if (k < MEM) {
            #pragma unroll
            for (int j = 0; j < 5; ++j)
                acc += convt_w[j] * mem_W[k * FEA + n + 4 - j];
        }
        wc[n * 64 + k] = (__bf16)acc;
        return;
    }

    if (blockIdx.x >= 2048) {              // ---- att softmax ----
        const int b0 = (blockIdx.x - 2048) * 16;
        int m = lane < MEM ? lane : MEM - 1;
        float dwv[DATE];
        const f32x4* dwp = (const f32x4*)(dW + m * DATE);
        #pragma unroll
        for (int c = 0; c < 8; ++c) {
            f32x4 v = dwp[c];
            #pragma unroll
            for (int j = 0; j < 4; ++j) dwv[c * 4 + j] = v[j];
        }
        #pragma unroll
        for (int rr = 0; rr < 4; ++rr) {
            int r = b0 + wid * 4 + rr;
            const f32x4* dvp = (const f32x4*)(dv + (size_t)r * DATE);
            float sc = 0.f;
            #pragma unroll
            for (int c = 0; c < 8; ++c) {
                f32x4 v = dvp[c];
                #pragma unroll
                for (int j = 0; j < 4; ++j) sc += v[j] * dwv[c * 4 + j];
            }
            float scm = (lane < MEM) ? sc : -1e30f;
            float mx  = wave_max(scm);
            float e   = (lane < MEM) ? __expf(sc - mx) : 0.f;
            float s   = wave_sum(e);
            float p   = e / s;
            float d   = p - 0.0025f;
            float p2  = (d > 0.f) ? p * d / (d + 1e-12f) : 0.f;
            float s2  = wave_sum(p2) + 1e-12f;
            float att = p2 / s2;
            att_g[(size_t)r * 64 + lane] = (lane < MEM) ? (__bf16)att : (__bf16)0.f;
        }
        return;
    }

    // ---- wb GEMV: 16 rows/block, 4 rows/wave, full-row contiguous loads ----
    const int b0 = blockIdx.x * 16;
    f32x4 wv[4], bv[4];
    #pragma unroll
    for (int c = 0; c < 4; ++c) {
        wv[c] = *(const f32x4*)(fcw_w + c * 256 + lane * 4);
        bv[c] = *(const f32x4*)(fcb_w + c * 256 + lane * 4);
    }
    f32x4 xv[4][4];
    #pragma unroll
    for (int rr = 0; rr < 4; ++rr)
        #pragma unroll
        for (int c = 0; c < 4; ++c)
            xv[rr][c] = *(const f32x4*)(x + (size_t)(b0 + wid * 4 + rr) * LL
                                          + c * 256 + lane * 4);
    float fwb = fcw_b[0], fbb = fcb_b[0];
    #pragma unroll
    for (int rr = 0; rr < 4; ++rr) {
        int r = wid * 4 + rr;
        float aw = 0.f, ab = 0.f;
        #pragma unroll
        for (int c = 0; c < 4; ++c)
            #pragma unroll
            for (int j = 0; j < 4; ++j) {
                aw += xv[rr][c][j] * wv[c][j];
                ab += xv[rr][c][j] * bv[c][j];
            }
        #pragma unroll
        for (int off = 1; off <= 32; off <<= 1) {
            aw += __shfl_xor(aw, off);
            ab += __shfl_xor(ab, off);
        }
        if (lane == 0) {
            out[(size_t)BB * LL + (b0 + r)]      = fast_tanh(aw + fwb) * 0.5f + 1.0f;
            out[(size_t)BB * LL + BB + (b0 + r)] = fast_tanh(ab + fbb) * 0.5f;
        }
    }
}

// ---------------- K2: persistent store-streaming waves ---------------------
// Loop-order inversion: each wave pins its 64-column slice of wc in REGISTERS
// (8x bf16x8 = 32 VGPR, loaded once), then streams 16 batch-groups; per group:
// {2 att b128 loads + 2 wb loads -> 8 MFMA -> 4x 1KB stores}. No LDS, no
// barrier, no shfl; iterations independent -> loads pipeline across groups;
// each wave issues 64 KB of stores nearly back-to-back per pass.
// DIAGNOSTIC x2: the p-loop writes the full output twice (idempotent) so this
// dispatch exceeds the 79us fill threshold and returns its own counters.
// wave id = blockIdx.x*4+wid in [0,2048): slice = id&15 (n0 = slice*64),
// gbase = id>>4 in [0,128) -> groups gbase*16..+16 (16 batches each).
__global__ __launch_bounds__(256) void memconv_persist(
        const __bf16* __restrict__ wc,
        const __bf16* __restrict__ att_g,
        const float* __restrict__ wb,      // = out + BB*LL (w at 0, b at +BB)
        float* __restrict__ out) {
    const int lane  = threadIdx.x & 63;
    const int wid   = threadIdx.x >> 6;
    const int cg    = lane & 15;
    const int kg    = lane >> 4;
    const int wave  = blockIdx.x * 4 + wid;
    const int slice = wave & 15;
    const int gbase = wave >> 4;
    const int n0    = slice * 64;

    // wc A-fragments for this wave's 4 n-tiles: resident for the whole kernel
    bf16x8 a0[4], a1[4];
    #pragma unroll
    for (int t = 0; t < 4; ++t) {
        int n = n0 + t * 16 + cg;
        a0[t] = *(const bf16x8*)(wc + n * 64 + kg * 8);
        a1[t] = *(const bf16x8*)(wc + n * 64 + 32 + kg * 8);
    }

    for (int p = 0; p < 2; ++p) {          // x2 pass: visibility diagnostic
        #pragma unroll 2
        for (int gi = 0; gi < 16; ++gi) {
            const int g16 = (gbase * 16 + gi) * 16;   // first batch of group
            bf16x8 bf0 = *(const bf16x8*)(att_g + (size_t)(g16 + cg) * 64 + kg * 8);
            bf16x8 bf1 = *(const bf16x8*)(att_g + (size_t)(g16 + cg) * 64 + 32 + kg * 8);
            float  w   = wb[g16 + cg];
            float  bi  = wb[BB + g16 + cg];
            float* dst = out + (size_t)(g16 + cg) * LL + n0 + kg * 4;
            #pragma unroll
            for (int t = 0; t < 4; ++t) {
                f32x4 z = {0.f, 0.f, 0.f, 0.f};
                z = __builtin_amdgcn_mfma_f32_16x16x32_bf16(a0[t], bf0, z, 0, 0, 0);
                z = __builtin_amdgcn_mfma_f32_16x16x32_bf16(a1[t], bf1, z, 0, 0, 0);
                f32x4 o;
                #pragma unroll
                for (int k = 0; k < 4; ++k) o[k] = z[k] * w + bi;
                *(f32x4*)(dst + t * 16) = o;
            }
        }
    }
}

extern "C" void kernel_launch(void* const* d_in, const int* in_sizes, int n_in,
                              void* d_out, int out_size, void* d_ws, size_t ws_size,
                              hipStream_t stream) {
    const float* x     = (const float*)d_in[0];
    const float* dv    = (const float*)d_in[1];
    // d_in[2] = conv_w: DEAD CODE in the reference (st is overwritten by st_mem)
    const float* convt = (const float*)d_in[3];
    const float* memW  = (const float*)d_in[4];
    const float* dateW = (const float*)d_in[5];
    const float* fcww  = (const float*)d_in[6];
    const float* fcwb  = (const float*)d_in[7];
    const float* fcbw  = (const float*)d_in[8];
    const float* fcbb  = (const float*)d_in[9];
    float* out = (float*)d_out;
    __bf16* wc    = (__bf16*)d_ws;            // 65536 bf16 = 128 KB
    __bf16* att_g = (__bf16*)d_ws + 65536;    // 32768*64 bf16 = 4 MB

    prep_and_wb    <<<4352, 256, 0, stream>>>(convt, memW, x, fcww, fcwb, fcbw, fcbb,
                                              dv, dateW, wc, att_g, out);
    memconv_persist<<<512,  256, 0, stream>>>(wc, att_g, out + (size_t)BB * LL, out);
}